// Round 1
// baseline (1855.316 us; speedup 1.0000x reference)
//
#include <hip/hip_runtime.h>

typedef __attribute__((ext_vector_type(4))) float          f32x4;
typedef __attribute__((ext_vector_type(8))) short          bf16x8;
typedef __attribute__((ext_vector_type(4))) unsigned short us4;
typedef __attribute__((ext_vector_type(8))) unsigned short us8;

#define D_DIM 2048
#define I_DIM 768
#define NE    64
#define CAP   1024
#define NTOK  4096

__device__ __forceinline__ unsigned short f2bf(float f) {
  union { float f; unsigned u; } c; c.f = f;
  unsigned r = c.u + 0x7fffu + ((c.u >> 16) & 1u);
  return (unsigned short)(r >> 16);
}
__device__ __forceinline__ unsigned pack2(float a, float b) {
  return (unsigned)f2bf(a) | ((unsigned)f2bf(b) << 16);
}

// ---------------- router: logits (fp32), top-8, renorm, dispatch ----------------
__global__ __launch_bounds__(256) void k_router(
    const float* __restrict__ x, const float* __restrict__ rw,
    int* __restrict__ counts, int* __restrict__ slot_token,
    float* __restrict__ slot_w)
{
  const int lane = threadIdx.x & 63;
  const int tok  = blockIdx.x * 4 + (threadIdx.x >> 6);
  const float* xr = x + (size_t)tok * D_DIM;

  float acc = 0.f;
  for (int d0 = 0; d0 < D_DIM; d0 += 64) {
    float xv = xr[d0 + lane];
    #pragma unroll
    for (int j = 0; j < 64; ++j) {
      float xj = __shfl(xv, j, 64);
      acc = fmaf(xj, rw[(size_t)(d0 + j) * NE + lane], acc);
    }
  }

  // iterative top-8 over 64 lanes (tie -> lower expert index, matches lax.top_k)
  float v = acc; int vi = lane;
  float wk[8]; int ei[8];
  float mx0 = 0.f, wsum = 0.f;
  #pragma unroll
  for (int k = 0; k < 8; ++k) {
    float mv = v; int mi = vi;
    #pragma unroll
    for (int off = 32; off >= 1; off >>= 1) {
      float ov = __shfl_xor(mv, off, 64);
      int   oi = __shfl_xor(mi, off, 64);
      if (ov > mv || (ov == mv && oi < mi)) { mv = ov; mi = oi; }
    }
    if (k == 0) mx0 = mv;
    float ew = __expf(mv - mx0);
    wk[k] = ew; ei[k] = mi; wsum += ew;
    if (lane == mi) v = -3.4e38f;
  }

  if (lane == 0) {
    float inv = 1.f / wsum;
    #pragma unroll
    for (int k = 0; k < 8; ++k) {
      int ee   = ei[k];
      int slot = atomicAdd(&counts[ee], 1);
      if (slot < CAP) {
        slot_token[ee * CAP + slot] = tok;
        slot_w[ee * CAP + slot]     = wk[k] * inv;
      }
    }
  }
}

// ---------------- gate/up fused GEMM + SwiGLU -> h (bf16) ----------------
// grid: (mt=8, nt=12, e=64), block 256. Tile: 128 slots x 64 i, BK=64.
__global__ __launch_bounds__(256) void k_mlp1(
    const float* __restrict__ x, const float* __restrict__ gate,
    const float* __restrict__ up, const int* __restrict__ counts,
    const int* __restrict__ slot_token, unsigned short* __restrict__ h)
{
  const int e  = blockIdx.z;
  const int mt = blockIdx.x;
  const int nt = blockIdx.y;
  int cnt = counts[e]; if (cnt > CAP) cnt = CAP;
  const int m0 = mt * 128;
  if (m0 >= cnt) return;
  const int n0 = nt * 64;

  const int t    = threadIdx.x;
  const int lane = t & 63;
  const int wv   = t >> 6;

  __shared__ unsigned short As[128][72];
  __shared__ unsigned short Bg[64][72];
  __shared__ unsigned short Bu[64][72];

  // A staging map: row = (t>>4) + 16*it, col4 = (t&15)*4
  const int ar = t >> 4;
  const int ac = (t & 15) * 4;
  int tokr[8];
  #pragma unroll
  for (int it = 0; it < 8; ++it) {
    int slot = m0 + ar + it * 16;
    int tk = slot_token[e * CAP + slot];   // in-bounds read; may be stale
    tokr[it] = (slot < cnt) ? tk : 0;
  }

  // B staging: n-quad bq=(t&15)*4, k-pair base bs=(t>>4)*2, k = bs + 32*kit
  const int bq = (t & 15) * 4;
  const int bs = (t >> 4) * 2;
  const float* gb = gate + (size_t)e * D_DIM * I_DIM + n0;
  const float* ub = up   + (size_t)e * D_DIM * I_DIM + n0;

  f32x4 ag[2][4], au[2][4];
  #pragma unroll
  for (int m = 0; m < 2; ++m)
    #pragma unroll
    for (int n = 0; n < 4; ++n) {
      f32x4 z = {0.f, 0.f, 0.f, 0.f};
      ag[m][n] = z; au[m][n] = z;
    }

  for (int kk = 0; kk < D_DIM; kk += 64) {
    // stage A (gathered x rows, fp32 -> bf16)
    #pragma unroll
    for (int it = 0; it < 8; ++it) {
      const float4 vx = *(const float4*)(x + (size_t)tokr[it] * D_DIM + kk + ac);
      us4 b; b.x = f2bf(vx.x); b.y = f2bf(vx.y); b.z = f2bf(vx.z); b.w = f2bf(vx.w);
      *(us4*)&As[ar + it * 16][ac] = b;
    }
    // stage Bg/Bu transposed: Bt[n][k], paired (k,k+1) b32 writes
    #pragma unroll
    for (int kit = 0; kit < 2; ++kit) {
      const int k = bs + kit * 32;
      const float4 g0 = *(const float4*)(gb + (size_t)(kk + k    ) * I_DIM + bq);
      const float4 g1 = *(const float4*)(gb + (size_t)(kk + k + 1) * I_DIM + bq);
      const float4 u0 = *(const float4*)(ub + (size_t)(kk + k    ) * I_DIM + bq);
      const float4 u1 = *(const float4*)(ub + (size_t)(kk + k + 1) * I_DIM + bq);
      *(unsigned*)&Bg[bq + 0][k] = pack2(g0.x, g1.x);
      *(unsigned*)&Bg[bq + 1][k] = pack2(g0.y, g1.y);
      *(unsigned*)&Bg[bq + 2][k] = pack2(g0.z, g1.z);
      *(unsigned*)&Bg[bq + 3][k] = pack2(g0.w, g1.w);
      *(unsigned*)&Bu[bq + 0][k] = pack2(u0.x, u1.x);
      *(unsigned*)&Bu[bq + 1][k] = pack2(u0.y, u1.y);
      *(unsigned*)&Bu[bq + 2][k] = pack2(u0.z, u1.z);
      *(unsigned*)&Bu[bq + 3][k] = pack2(u0.w, u1.w);
    }
    __syncthreads();

    {
      const int li = lane & 15;
      const int gq = lane >> 4;
      const int r0 = wv * 32;
      #pragma unroll
      for (int kc = 0; kc < 2; ++kc) {
        const int ko = kc * 32 + gq * 8;
        bf16x8 a0 = *(const bf16x8*)&As[r0 + li][ko];
        bf16x8 a1 = *(const bf16x8*)&As[r0 + 16 + li][ko];
        #pragma unroll
        for (int n = 0; n < 4; ++n) {
          bf16x8 vg = *(const bf16x8*)&Bg[n * 16 + li][ko];
          bf16x8 vu = *(const bf16x8*)&Bu[n * 16 + li][ko];
          ag[0][n] = __builtin_amdgcn_mfma_f32_16x16x32_bf16(a0, vg, ag[0][n], 0, 0, 0);
          ag[1][n] = __builtin_amdgcn_mfma_f32_16x16x32_bf16(a1, vg, ag[1][n], 0, 0, 0);
          au[0][n] = __builtin_amdgcn_mfma_f32_16x16x32_bf16(a0, vu, au[0][n], 0, 0, 0);
          au[1][n] = __builtin_amdgcn_mfma_f32_16x16x32_bf16(a1, vu, au[1][n], 0, 0, 0);
        }
      }
    }
    __syncthreads();
  }

  // epilogue: h = silu(g) * u  (bf16 store)
  const int li = lane & 15;
  const int r4 = (lane >> 4) * 4;
  #pragma unroll
  for (int m = 0; m < 2; ++m) {
    #pragma unroll
    for (int j = 0; j < 4; ++j) {
      const int slot = m0 + wv * 32 + m * 16 + r4 + j;
      unsigned short* hrow = h + (size_t)(e * CAP + slot) * I_DIM + n0 + li;
      #pragma unroll
      for (int n = 0; n < 4; ++n) {
        float gg = ag[m][n][j];
        float uu = au[m][n][j];
        float hv = gg * uu / (1.f + __expf(-gg));
        hrow[n * 16] = f2bf(hv);
      }
    }
  }
}

// ---------------- down GEMM + weighted scatter-add into out ----------------
// grid: (mt=8, nt=16, e=64), block 256. Tile: 128 slots x 128 d, BK=64.
__global__ __launch_bounds__(256) void k_mlp2(
    const unsigned short* __restrict__ h, const float* __restrict__ down,
    const int* __restrict__ counts, const int* __restrict__ slot_token,
    const float* __restrict__ slot_w, float* __restrict__ out)
{
  const int e  = blockIdx.z;
  const int mt = blockIdx.x;
  const int nt = blockIdx.y;
  int cnt = counts[e]; if (cnt > CAP) cnt = CAP;
  const int m0 = mt * 128;
  if (m0 >= cnt) return;
  const int n0 = nt * 128;

  const int t    = threadIdx.x;
  const int lane = t & 63;
  const int wv   = t >> 6;
  const int wm   = (wv >> 1) * 64;
  const int wn   = (wv & 1) * 64;

  __shared__ unsigned short As[128][72];
  __shared__ unsigned short Bt[128][72];

  const int ar = t >> 3;            // 0..31
  const int ac = (t & 7) * 8;       // 0..56
  const int bq = (t & 15) * 4;
  const int bs = (t >> 4) * 2;

  const unsigned short* hb = h + (size_t)e * CAP * I_DIM;
  const float* db = down + (size_t)e * I_DIM * D_DIM + n0;

  f32x4 acc[4][4];
  #pragma unroll
  for (int m = 0; m < 4; ++m)
    #pragma unroll
    for (int n = 0; n < 4; ++n) { f32x4 z = {0.f,0.f,0.f,0.f}; acc[m][n] = z; }

  for (int kk = 0; kk < I_DIM; kk += 64) {
    // stage A (h, already bf16): 16B vector copies
    #pragma unroll
    for (int it = 0; it < 4; ++it) {
      const int row = ar + it * 32;
      us8 av = *(const us8*)(hb + (size_t)(m0 + row) * I_DIM + kk + ac);
      *(us8*)&As[row][ac] = av;
    }
    // stage B transposed (down weights fp32 -> bf16), two 64-col halves
    #pragma unroll
    for (int hl = 0; hl < 2; ++hl) {
      #pragma unroll
      for (int kit = 0; kit < 2; ++kit) {
        const int k = bs + kit * 32;
        const int n = hl * 64 + bq;
        const float4 d0v = *(const float4*)(db + (size_t)(kk + k    ) * D_DIM + n);
        const float4 d1v = *(const float4*)(db + (size_t)(kk + k + 1) * D_DIM + n);
        *(unsigned*)&Bt[n + 0][k] = pack2(d0v.x, d1v.x);
        *(unsigned*)&Bt[n + 1][k] = pack2(d0v.y, d1v.y);
        *(unsigned*)&Bt[n + 2][k] = pack2(d0v.z, d1v.z);
        *(unsigned*)&Bt[n + 3][k] = pack2(d0v.w, d1v.w);
      }
    }
    __syncthreads();

    {
      const int li = lane & 15;
      const int gq = lane >> 4;
      #pragma unroll
      for (int kc = 0; kc < 2; ++kc) {
        const int ko = kc * 32 + gq * 8;
        bf16x8 a[4], b[4];
        #pragma unroll
        for (int m = 0; m < 4; ++m) a[m] = *(const bf16x8*)&As[wm + m * 16 + li][ko];
        #pragma unroll
        for (int n = 0; n < 4; ++n) b[n] = *(const bf16x8*)&Bt[wn + n * 16 + li][ko];
        #pragma unroll
        for (int m = 0; m < 4; ++m)
          #pragma unroll
          for (int n = 0; n < 4; ++n)
            acc[m][n] = __builtin_amdgcn_mfma_f32_16x16x32_bf16(a[m], b[n], acc[m][n], 0, 0, 0);
      }
    }
    __syncthreads();
  }

  // epilogue: out[tok][d] += w * y   (device-scope fp32 atomics)
  const int li = lane & 15;
  const int r4 = (lane >> 4) * 4;
  #pragma unroll
  for (int m = 0; m < 4; ++m) {
    #pragma unroll
    for (int j = 0; j < 4; ++j) {
      const int slot = m0 + wm + m * 16 + r4 + j;
      if (slot < cnt) {
        const int   tk  = slot_token[e * CAP + slot];
        const float wgt = slot_w[e * CAP + slot];
        float* orow = out + (size_t)tk * D_DIM + n0 + wn + li;
        #pragma unroll
        for (int n = 0; n < 4; ++n)
          atomicAdd(&orow[n * 16], wgt * acc[m][n][j]);
      }
    }
  }
}

extern "C" void kernel_launch(void* const* d_in, const int* in_sizes, int n_in,
                              void* d_out, int out_size, void* d_ws, size_t ws_size,
                              hipStream_t stream) {
  const float* x    = (const float*)d_in[0];
  const float* rw   = (const float*)d_in[1];
  const float* gate = (const float*)d_in[2];
  const float* up   = (const float*)d_in[3];
  const float* down = (const float*)d_in[4];
  float* out = (float*)d_out;

  char* ws = (char*)d_ws;
  int*   counts     = (int*)ws;                                   // 256 B
  int*   slot_token = (int*)(ws + 1024);                          // 256 KB
  float* slot_w     = (float*)(ws + 1024 + (size_t)NE * CAP * 4); // 256 KB
  unsigned short* h = (unsigned short*)(ws + 1024 + (size_t)NE * CAP * 8); // 100.7 MB

  hipMemsetAsync(counts, 0, NE * sizeof(int), stream);
  hipMemsetAsync(out, 0, (size_t)out_size * sizeof(float), stream);

  k_router<<<dim3(NTOK / 4), 256, 0, stream>>>(x, rw, counts, slot_token, slot_w);
  k_mlp1<<<dim3(8, 12, NE), 256, 0, stream>>>(x, gate, up, counts, slot_token, h);
  k_mlp2<<<dim3(8, 16, NE), 256, 0, stream>>>(h, down, counts, slot_token, slot_w, out);
}